// Round 13
// baseline (107.854 us; speedup 1.0000x reference)
//
#include <hip/hip_runtime.h>
#include <stdint.h>
#include <math.h>

#define NB 256      // graphs (B)
#define NN 256      // nodes at level 0
#define HC 32       // hidden channels
#define EMBD 256    // embedding dim
#define NF 9        // atom feat cols
#define NV 128      // padded vocab
#define TPB 1024    // 16 waves -> 4/SIMD (1 block/CU; grid == CU count)

typedef unsigned int u32;
typedef unsigned long long u64;

// ---------------------------------------------------------------------------
// TW[f,v,c] = sum_e table[f,v,e] * W0[e,c]
__global__ void k_tw(const float* __restrict__ table, const float* __restrict__ W0,
                     float* __restrict__ TW) {
    int gid = blockIdx.x * 256 + threadIdx.x;
    if (gid >= NF * NV * HC) return;
    int c = gid & 31;
    int v = (gid >> 5) & (NV - 1);
    int f = gid >> 12;
    const float* trow = table + (size_t)(f * NV + v) * EMBD;
    float acc = 0.f;
    for (int e = 0; e < EMBD; ++e) acc += trow[e] * W0[e * HC + c];
    TW[gid] = acc;
}

// ---------------------------------------------------------------------------
// LDS layout (byte offsets), total 136320 <= 160 KiB
#define SM_BITS   0        // u32[2048]
#define SM_DI0    8192     // f[256]
#define SM_BIG0   9216     // z0raw stride36 (36KB) -> Ag0 u8[128*128] (16KB)
#define SM_X1     46080    // f[128*36]
#define SM_BIG1   64512    // f[4608]: xg0 / Ag1 f32[64*64] / dec128[128*36]
#define SM_X2     82944    // f[64*36]
#define SM_BIG2   92160    // f[2304]: Ag2[1024] + x3@+1024; dec64[64*36]
#define SM_ZB     101376   // f[4608]: z stride36; xg@+2304; Gb u32[64*33]
#define SM_WG     119808   // Pg u32[128*9] / Wl f[32*36]  (4608B)
#define SM_SC     124416   // f[256]
#define SM_KEYS   125440   // u64[256]  (16B aligned)
#define SM_IDX0   127488
#define SM_VALS0  128000
#define SM_INV0   128512
#define SM_IDX1   129536
#define SM_VALS1  129792
#define SM_INV1   130048
#define SM_IDX2   130560
#define SM_VALS2  130688
#define SM_INV2   130816
#define SM_DI1    131072
#define SM_DI2    131584
#define SM_DI3    131840
#define SM_PART   131968   // f[1056] (32 groups x 33)
#define SM_GL     136192   // f[32]
#define SM_TOTAL  136320

__device__ __forceinline__ u32 dot4acc(u32 a, u32 b, u32 c) {
#if __has_builtin(__builtin_amdgcn_udot4)
    return __builtin_amdgcn_udot4(a, b, c, false);
#else
    return c + (a & 0xffu) * (b & 0xffu) + ((a >> 8) & 0xffu) * ((b >> 8) & 0xffu)
         + ((a >> 16) & 0xffu) * ((b >> 16) & 0xffu) + (a >> 24) * (b >> 24);
#endif
}

// fast tanh via hardware exp: rel err ~1e-6 (score gaps ~1e-3; safe for topk)
__device__ __forceinline__ float ftanh(float x) {
    float ax = fabsf(x);
    float e = __expf(-2.f * ax);
    float tv = (1.f - e) / (1.f + e);
    return copysignf(tv, x);
}

__device__ __forceinline__ u64 mkkey(float s, int r) {
    u32 bits = __float_as_uint(s);
    u32 m = ((int)bits < 0) ? 0xFFFFFFFFu : 0x80000000u;
    return ((u64)(~(bits ^ m)) << 32) | (u32)r;
}

// rank pass with ulonglong2 key reads (halved LDS issue count)
template <int N, int K>
__device__ __forceinline__ void rank_pass(const float* sc, const u64* keys,
                                          int* idxo, float* valso, int* invo, int t) {
    if (t < N) {
        u64 mykey = keys[t];
        const ulonglong2* k2 = reinterpret_cast<const ulonglong2*>(keys);
        int rank = 0;
#pragma unroll 8
        for (int j = 0; j < N / 2; ++j) {
            ulonglong2 kk = k2[j];
            rank += (kk.x < mykey) ? 1 : 0;
            rank += (kk.y < mykey) ? 1 : 0;
        }
        if (rank < K) {
            idxo[rank] = t;
            valso[rank] = sc[t];
            invo[t] = rank;
        }
    }
    __syncthreads();
}

template <int N>
__device__ __forceinline__ void az_f32(const float* A, const float* z,
                                       const float* di, const float* __restrict__ bias,
                                       float* xout, int t) {
    if (t < N * 8) {
        int r = t >> 3, cq = (t & 7) * 4;
        float a0 = 0.f, a1 = 0.f, a2 = 0.f, a3 = 0.f;
        for (int jj = 0; jj < N; ++jj) {
            const float4 zv = *reinterpret_cast<const float4*>(&z[jj * 36 + cq]);
            float a = A[jj * N + r];
            a0 += a * zv.x; a1 += a * zv.y; a2 += a * zv.z; a3 += a * zv.w;
        }
        float dr = di[r];
        float4 o;
        o.x = fmaxf(dr * (a0 + 2.f * z[r * 36 + cq + 0]) + bias[cq + 0], 0.f);
        o.y = fmaxf(dr * (a1 + 2.f * z[r * 36 + cq + 1]) + bias[cq + 1], 0.f);
        o.z = fmaxf(dr * (a2 + 2.f * z[r * 36 + cq + 2]) + bias[cq + 2], 0.f);
        o.w = fmaxf(dr * (a3 + 2.f * z[r * 36 + cq + 3]) + bias[cq + 3], 0.f);
        *reinterpret_cast<float4*>(&xout[r * 36 + cq]) = o;
    }
    __syncthreads();
}

// 2 rows/thread + explicit 2-stage pipeline (load jj+1 before FMA of jj)
template <int N>
__device__ __forceinline__ void az2_f32(const float* A, const float* z,
                                        const float* di, const float* __restrict__ bias,
                                        float* xout, int t) {
    if (t < N * 4) {
        int g = t >> 3, cq = (t & 7) * 4;
        float a0[4] = {0.f, 0.f, 0.f, 0.f};
        float a1[4] = {0.f, 0.f, 0.f, 0.f};
        float4 zc = *reinterpret_cast<const float4*>(&z[cq]);
        float2 ac = *reinterpret_cast<const float2*>(&A[2 * g]);
        for (int jj = 0; jj < N - 1; ++jj) {
            const float4 zn = *reinterpret_cast<const float4*>(&z[(jj + 1) * 36 + cq]);
            const float2 an = *reinterpret_cast<const float2*>(&A[(jj + 1) * N + 2 * g]);
            a0[0] += ac.x * zc.x; a0[1] += ac.x * zc.y;
            a0[2] += ac.x * zc.z; a0[3] += ac.x * zc.w;
            a1[0] += ac.y * zc.x; a1[1] += ac.y * zc.y;
            a1[2] += ac.y * zc.z; a1[3] += ac.y * zc.w;
            zc = zn; ac = an;
        }
        a0[0] += ac.x * zc.x; a0[1] += ac.x * zc.y;
        a0[2] += ac.x * zc.z; a0[3] += ac.x * zc.w;
        a1[0] += ac.y * zc.x; a1[1] += ac.y * zc.y;
        a1[2] += ac.y * zc.z; a1[3] += ac.y * zc.w;
#pragma unroll
        for (int i = 0; i < 2; ++i) {
            int r = 2 * g + i;
            const float* ai = i ? a1 : a0;
            float dr = di[r];
            float4 o;
            o.x = fmaxf(dr * (ai[0] + 2.f * z[r * 36 + cq + 0]) + bias[cq + 0], 0.f);
            o.y = fmaxf(dr * (ai[1] + 2.f * z[r * 36 + cq + 1]) + bias[cq + 1], 0.f);
            o.z = fmaxf(dr * (ai[2] + 2.f * z[r * 36 + cq + 2]) + bias[cq + 2], 0.f);
            o.w = fmaxf(dr * (ai[3] + 2.f * z[r * 36 + cq + 3]) + bias[cq + 3], 0.f);
            *reinterpret_cast<float4*>(&xout[r * 36 + cq]) = o;
        }
    }
    __syncthreads();
}

// 4 rows/thread + explicit 2-stage pipeline
__device__ __forceinline__ void az_u8(const u32* AgW, const float* z,
                                      const float* di, const float* __restrict__ bias,
                                      float* xout, int t) {
    if (t < 256) {
        int g = t >> 3, cq = (t & 7) * 4;
        float ax[4][4];
#pragma unroll
        for (int i = 0; i < 4; ++i) { ax[i][0] = ax[i][1] = ax[i][2] = ax[i][3] = 0.f; }
        float4 zc = *reinterpret_cast<const float4*>(&z[cq]);
        u32 wc = AgW[g];
        for (int jj = 0; jj < 127; ++jj) {
            const float4 zn = *reinterpret_cast<const float4*>(&z[(jj + 1) * 36 + cq]);
            u32 wn = AgW[(jj + 1) * 32 + g];
            float f0 = (float)(wc & 255u), f1 = (float)((wc >> 8) & 255u);
            float f2 = (float)((wc >> 16) & 255u), f3 = (float)(wc >> 24);
            ax[0][0] += f0 * zc.x; ax[0][1] += f0 * zc.y; ax[0][2] += f0 * zc.z; ax[0][3] += f0 * zc.w;
            ax[1][0] += f1 * zc.x; ax[1][1] += f1 * zc.y; ax[1][2] += f1 * zc.z; ax[1][3] += f1 * zc.w;
            ax[2][0] += f2 * zc.x; ax[2][1] += f2 * zc.y; ax[2][2] += f2 * zc.z; ax[2][3] += f2 * zc.w;
            ax[3][0] += f3 * zc.x; ax[3][1] += f3 * zc.y; ax[3][2] += f3 * zc.z; ax[3][3] += f3 * zc.w;
            zc = zn; wc = wn;
        }
        {
            float f0 = (float)(wc & 255u), f1 = (float)((wc >> 8) & 255u);
            float f2 = (float)((wc >> 16) & 255u), f3 = (float)(wc >> 24);
            ax[0][0] += f0 * zc.x; ax[0][1] += f0 * zc.y; ax[0][2] += f0 * zc.z; ax[0][3] += f0 * zc.w;
            ax[1][0] += f1 * zc.x; ax[1][1] += f1 * zc.y; ax[1][2] += f1 * zc.z; ax[1][3] += f1 * zc.w;
            ax[2][0] += f2 * zc.x; ax[2][1] += f2 * zc.y; ax[2][2] += f2 * zc.z; ax[2][3] += f2 * zc.w;
            ax[3][0] += f3 * zc.x; ax[3][1] += f3 * zc.y; ax[3][2] += f3 * zc.z; ax[3][3] += f3 * zc.w;
        }
#pragma unroll
        for (int i = 0; i < 4; ++i) {
            int r = 4 * g + i;
            float dr = di[r];
            float4 o;
            o.x = fmaxf(dr * (ax[i][0] + 2.f * z[r * 36 + cq + 0]) + bias[cq + 0], 0.f);
            o.y = fmaxf(dr * (ax[i][1] + 2.f * z[r * 36 + cq + 1]) + bias[cq + 1], 0.f);
            o.z = fmaxf(dr * (ax[i][2] + 2.f * z[r * 36 + cq + 2]) + bias[cq + 2], 0.f);
            o.w = fmaxf(dr * (ax[i][3] + 2.f * z[r * 36 + cq + 3]) + bias[cq + 3], 0.f);
            *reinterpret_cast<float4*>(&xout[r * 36 + cq]) = o;
        }
    }
    __syncthreads();
}

// z[r,:] = pre[r] * xin[r,:] @ Wl — xin read as float4 (rows 144B-aligned)
template <int N>
__device__ __forceinline__ void xw_mm(const float* xin, const float* Wl,
                                      const float* pre, float* zout, int t) {
    for (int i = t; i < N * 8; i += TPB) {
        int r = i >> 3, cq = (i & 7) * 4;
        float a0 = 0.f, a1 = 0.f, a2 = 0.f, a3 = 0.f;
#pragma unroll
        for (int e4 = 0; e4 < 8; ++e4) {
            const float4 xv = *reinterpret_cast<const float4*>(&xin[r * 36 + e4 * 4]);
            const float4 w0 = *reinterpret_cast<const float4*>(&Wl[(e4 * 4 + 0) * 36 + cq]);
            const float4 w1 = *reinterpret_cast<const float4*>(&Wl[(e4 * 4 + 1) * 36 + cq]);
            const float4 w2 = *reinterpret_cast<const float4*>(&Wl[(e4 * 4 + 2) * 36 + cq]);
            const float4 w3 = *reinterpret_cast<const float4*>(&Wl[(e4 * 4 + 3) * 36 + cq]);
            a0 += xv.x * w0.x; a1 += xv.x * w0.y; a2 += xv.x * w0.z; a3 += xv.x * w0.w;
            a0 += xv.y * w1.x; a1 += xv.y * w1.y; a2 += xv.y * w1.z; a3 += xv.y * w1.w;
            a0 += xv.z * w2.x; a1 += xv.z * w2.y; a2 += xv.z * w2.z; a3 += xv.z * w2.w;
            a0 += xv.w * w3.x; a1 += xv.w * w3.y; a2 += xv.w * w3.z; a3 += xv.w * w3.w;
        }
        float p = pre ? pre[r] : 1.f;
        *reinterpret_cast<float4*>(&zout[r * 36 + cq]) =
            make_float4(a0 * p, a1 * p, a2 * p, a3 * p);
    }
    __syncthreads();
}

// fused skip-merge variant, vectorized the same way
template <int N>
__device__ __forceinline__ void xw_mrg(const float* xin, const float* xup,
                                       const int* invl, const float* Wl,
                                       const float* pre, float* zout, int t) {
    for (int i = t; i < N * 8; i += TPB) {
        int r = i >> 3, cq = (i & 7) * 4;
        int ir = invl[r];
        float a0 = 0.f, a1 = 0.f, a2 = 0.f, a3 = 0.f;
#pragma unroll
        for (int e4 = 0; e4 < 8; ++e4) {
            float4 xv = *reinterpret_cast<const float4*>(&xin[r * 36 + e4 * 4]);
            if (ir >= 0) {
                const float4 uv = *reinterpret_cast<const float4*>(&xup[ir * 36 + e4 * 4]);
                xv.x += uv.x; xv.y += uv.y; xv.z += uv.z; xv.w += uv.w;
            }
            const float4 w0 = *reinterpret_cast<const float4*>(&Wl[(e4 * 4 + 0) * 36 + cq]);
            const float4 w1 = *reinterpret_cast<const float4*>(&Wl[(e4 * 4 + 1) * 36 + cq]);
            const float4 w2 = *reinterpret_cast<const float4*>(&Wl[(e4 * 4 + 2) * 36 + cq]);
            const float4 w3 = *reinterpret_cast<const float4*>(&Wl[(e4 * 4 + 3) * 36 + cq]);
            a0 += xv.x * w0.x; a1 += xv.x * w0.y; a2 += xv.x * w0.z; a3 += xv.x * w0.w;
            a0 += xv.y * w1.x; a1 += xv.y * w1.y; a2 += xv.y * w1.z; a3 += xv.y * w1.w;
            a0 += xv.z * w2.x; a1 += xv.z * w2.y; a2 += xv.z * w2.z; a3 += xv.z * w2.w;
            a0 += xv.w * w3.x; a1 += xv.w * w3.y; a2 += xv.w * w3.z; a3 += xv.w * w3.w;
        }
        float p = pre[r];
        *reinterpret_cast<float4*>(&zout[r * 36 + cq]) =
            make_float4(a0 * p, a1 * p, a2 * p, a3 * p);
    }
    __syncthreads();
}

__device__ __forceinline__ void aug64_32(const float* A, const int* idxl,
                                         float* out, float* di3, int t) {
    if (t < 256) {
        int rr0 = t >> 3, sb = (t & 7) * 4;
        int ir = idxl[rr0];
        int is0 = idxl[sb], is1 = idxl[sb + 1], is2 = idxl[sb + 2], is3 = idxl[sb + 3];
        float c0 = 0.f, c1 = 0.f, c2 = 0.f, c3 = 0.f;
        for (int jj = 0; jj < 16; ++jj) {
            int jq = ((jj + rr0) & 15) * 4;
            const float4 ar = *reinterpret_cast<const float4*>(&A[ir * 64 + jq]);
            const float4 v0 = *reinterpret_cast<const float4*>(&A[is0 * 64 + jq]);
            const float4 v1 = *reinterpret_cast<const float4*>(&A[is1 * 64 + jq]);
            const float4 v2 = *reinterpret_cast<const float4*>(&A[is2 * 64 + jq]);
            const float4 v3 = *reinterpret_cast<const float4*>(&A[is3 * 64 + jq]);
            c0 += ar.x * v0.x + ar.y * v0.y + ar.z * v0.z + ar.w * v0.w;
            c1 += ar.x * v1.x + ar.y * v1.y + ar.z * v1.z + ar.w * v1.w;
            c2 += ar.x * v2.x + ar.y * v2.y + ar.z * v2.z + ar.w * v2.w;
            c3 += ar.x * v3.x + ar.y * v3.y + ar.z * v3.z + ar.w * v3.w;
        }
        float o0 = c0 + 2.f * A[ir * 64 + is0] + (ir == is0 ? 1.f : 0.f);
        float o1 = c1 + 2.f * A[ir * 64 + is1] + (ir == is1 ? 1.f : 0.f);
        float o2 = c2 + 2.f * A[ir * 64 + is2] + (ir == is2 ? 1.f : 0.f);
        float o3 = c3 + 2.f * A[ir * 64 + is3] + (ir == is3 ? 1.f : 0.f);
        if (rr0 == sb + 0) o0 = 0.f;
        if (rr0 == sb + 1) o1 = 0.f;
        if (rr0 == sb + 2) o2 = 0.f;
        if (rr0 == sb + 3) o3 = 0.f;
        *reinterpret_cast<float4*>(&out[rr0 * 32 + sb]) = make_float4(o0, o1, o2, o3);
        float ps = o0 + o1 + o2 + o3;
        ps += __shfl_xor(ps, 1);
        ps += __shfl_xor(ps, 2);
        ps += __shfl_xor(ps, 4);
        if ((t & 7) == 0) di3[rr0] = 1.0f / sqrtf(ps + 2.0f);
    }
    __syncthreads();
}

// ---------------------------------------------------------------------------
__global__ void __launch_bounds__(TPB, 1) k_mega(
    const float* __restrict__ adj, const float* __restrict__ TW,
    const int* __restrict__ xa,
    const float* __restrict__ bd0, const float* __restrict__ wd,
    const float* __restrict__ bd, const float* __restrict__ wp,
    const float* __restrict__ wu, const float* __restrict__ bu,
    const float* __restrict__ wul, const float* __restrict__ bul,
    float* __restrict__ gx0, float* __restrict__ outp) {
    __shared__ __align__(16) char SM[SM_TOTAL];
    u32*   bitsl = (u32*)(SM + SM_BITS);
    float* di0l  = (float*)(SM + SM_DI0);
    float* z0    = (float*)(SM + SM_BIG0);
    u32*   AgW   = (u32*)(SM + SM_BIG0);
    float* x1l   = (float*)(SM + SM_X1);
    float* big1  = (float*)(SM + SM_BIG1);
    float* x2l   = (float*)(SM + SM_X2);
    float* big2  = (float*)(SM + SM_BIG2);
    float* zbf   = (float*)(SM + SM_ZB);
    u32*   Pg    = (u32*)(SM + SM_WG);
    float* Wl    = (float*)(SM + SM_WG);
    float* scl   = (float*)(SM + SM_SC);
    u64*   keys  = (u64*)(SM + SM_KEYS);
    int*   idx0l = (int*)(SM + SM_IDX0);
    float* vals0l= (float*)(SM + SM_VALS0);
    int*   inv0l = (int*)(SM + SM_INV0);
    int*   idx1l = (int*)(SM + SM_IDX1);
    float* vals1l= (float*)(SM + SM_VALS1);
    int*   inv1l = (int*)(SM + SM_INV1);
    int*   idx2l = (int*)(SM + SM_IDX2);
    float* vals2l= (float*)(SM + SM_VALS2);
    int*   inv2l = (int*)(SM + SM_INV2);
    float* di1   = (float*)(SM + SM_DI1);
    float* di2   = (float*)(SM + SM_DI2);
    float* di3   = (float*)(SM + SM_DI3);
    float* part  = (float*)(SM + SM_PART);
    float* gl    = (float*)(SM + SM_GL);
    float* x3l   = big2 + 1024;
    float* dec64 = big2;
    float* dec128= big1;

    int b = blockIdx.x, t = threadIdx.x;

    // P1: z0raw = h @ W0 via TW gather
    for (int i = t; i < 2048; i += TPB) {
        int node = i >> 3, cq = (i & 7) * 4;
        const int* xr = xa + (b * NN + node) * NF;
        float ax = 0.f, ay = 0.f, azz = 0.f, aw = 0.f;
#pragma unroll
        for (int f = 0; f < NF; ++f) {
            int v = xr[f];
            const float4 tw = *reinterpret_cast<const float4*>(&TW[((f << 7) + v) * HC + cq]);
            ax += tw.x; ay += tw.y; azz += tw.z; aw += tw.w;
        }
        *reinterpret_cast<float4*>(&z0[node * 36 + cq]) = make_float4(ax, ay, azz, aw);
    }

    // P0: pack adjacency + di0 — float4 row loads + shuffle nibble pack
    {
        int lane = t & 63, wv = t >> 6;
        for (int row = wv; row < NN; row += 16) {
            const float4 av = *reinterpret_cast<const float4*>(
                &adj[((size_t)b * NN + row) * NN + lane * 4]);
            u32 nib = (av.x != 0.f ? 1u : 0u) | (av.y != 0.f ? 2u : 0u)
                    | (av.z != 0.f ? 4u : 0u) | (av.w != 0.f ? 8u : 0u);
            int pc = __popc(nib);
            u32 w2 = nib | (__shfl_xor(nib, 1) << 4);
            u32 w4 = w2 | (__shfl_xor(w2, 2) << 8);
            u32 w8 = w4 | (__shfl_xor(w4, 4) << 16);
            if ((lane & 7) == 0) bitsl[row * 8 + (lane >> 3)] = w8;
            pc += __shfl_xor(pc, 1);  pc += __shfl_xor(pc, 2);
            pc += __shfl_xor(pc, 4);  pc += __shfl_xor(pc, 8);
            pc += __shfl_xor(pc, 16); pc += __shfl_xor(pc, 32);
            if (lane == 0) di0l[row] = 1.0f / sqrtf((float)pc + 2.0f);
        }
    }
    if (t < 32) gl[t] = wp[t];
    __syncthreads();

    // P2: GCN0 sparse + topk0 scores/keys; x0 -> global
    {
        float sn0 = 0.f;
        for (int i = 0; i < HC; ++i) { float v = gl[i]; sn0 += v * v; }
        sn0 = sqrtf(sn0);
        int r0 = t >> 3, cq = (t & 7) * 4;
        for (int tile = 0; tile < 2; ++tile) {
            int r = tile * 128 + r0;
            u32 mw[8];
#pragma unroll
            for (int w = 0; w < 8; ++w) mw[w] = bitsl[r * 8 + w];
            float a0 = 0.f, a1 = 0.f, a2 = 0.f, a3 = 0.f;
#pragma unroll
            for (int w = 0; w < 8; ++w) {
                u32 m = mw[w];
                int base = w * 32;
                while (m) {
                    int j = base + __ffs(m) - 1;
                    m &= m - 1;
                    float dj = di0l[j];
                    const float4 zv = *reinterpret_cast<const float4*>(&z0[j * 36 + cq]);
                    a0 += dj * zv.x; a1 += dj * zv.y; a2 += dj * zv.z; a3 += dj * zv.w;
                }
            }
            float dr = di0l[r];
            float o0 = fmaxf(dr * (a0 + 2.f * dr * z0[r * 36 + cq + 0]) + bd0[cq + 0], 0.f);
            float o1 = fmaxf(dr * (a1 + 2.f * dr * z0[r * 36 + cq + 1]) + bd0[cq + 1], 0.f);
            float o2 = fmaxf(dr * (a2 + 2.f * dr * z0[r * 36 + cq + 2]) + bd0[cq + 2], 0.f);
            float o3 = fmaxf(dr * (a3 + 2.f * dr * z0[r * 36 + cq + 3]) + bd0[cq + 3], 0.f);
            *reinterpret_cast<float4*>(&gx0[((size_t)b * NN + r) * HC + cq]) =
                make_float4(o0, o1, o2, o3);
            float pd = o0 * gl[cq] + o1 * gl[cq + 1] + o2 * gl[cq + 2] + o3 * gl[cq + 3];
            pd += __shfl_xor(pd, 1);
            pd += __shfl_xor(pd, 2);
            pd += __shfl_xor(pd, 4);
            if ((t & 7) == 0) {
                float s = ftanh(pd / sn0);
                scl[r] = s;
                keys[r] = mkkey(s, r);
                inv0l[r] = -1;
            }
        }
    }
    __syncthreads();

    // P3: topk0 rank
    rank_pass<256, 128>(scl, keys, idx0l, vals0l, inv0l, t);

    // P4: gathered bits -> popcount augment -> Ag0 u8, fused di1
    {
        int r = t >> 3, w = t & 7;
        int row = idx0l[r];
        u32 word = bitsl[row * 8 + w];
        if (w == (row >> 5)) word |= (1u << (row & 31));
        Pg[r * 9 + w] = word;
    }
    __syncthreads();
    {
        int rr0 = t >> 4, sb = (t & 15) * 4;
        u32 rw[2][8];
#pragma unroll
        for (int rt = 0; rt < 2; ++rt)
#pragma unroll
            for (int w = 0; w < 8; ++w) rw[rt][w] = Pg[(rt * 64 + rr0) * 9 + w];
        int rs0 = 0, rs1 = 0;
#pragma unroll
        for (int k4 = 0; k4 < 2; ++k4) {
            int s0 = sb + 64 * k4;
            u32 cnt[2][4];
#pragma unroll
            for (int a = 0; a < 2; ++a) { cnt[a][0] = cnt[a][1] = cnt[a][2] = cnt[a][3] = 0; }
#pragma unroll
            for (int u = 0; u < 4; ++u) {
                int s = s0 + u;
#pragma unroll
                for (int w = 0; w < 8; ++w) {
                    u32 sw = Pg[s * 9 + w];
                    cnt[0][u] += __popc(rw[0][w] & sw);
                    cnt[1][u] += __popc(rw[1][w] & sw);
                }
            }
#pragma unroll
            for (int rt = 0; rt < 2; ++rt) {
                int r = rt * 64 + rr0;
                if (r >= s0 && r < s0 + 4) cnt[rt][r - s0] = 0;
                AgW[r * 32 + (s0 >> 2)] =
                    cnt[rt][0] | (cnt[rt][1] << 8) | (cnt[rt][2] << 16) | (cnt[rt][3] << 24);
                int sum4 = (int)(cnt[rt][0] + cnt[rt][1] + cnt[rt][2] + cnt[rt][3]);
                if (rt == 0) rs0 += sum4; else rs1 += sum4;
            }
        }
        rs0 += __shfl_xor(rs0, 1); rs0 += __shfl_xor(rs0, 2);
        rs0 += __shfl_xor(rs0, 4); rs0 += __shfl_xor(rs0, 8);
        rs1 += __shfl_xor(rs1, 1); rs1 += __shfl_xor(rs1, 2);
        rs1 += __shfl_xor(rs1, 4); rs1 += __shfl_xor(rs1, 8);
        if ((t & 15) == 0) {
            di1[rr0]      = 1.0f / sqrtf((float)rs0 + 2.0f);
            di1[rr0 + 64] = 1.0f / sqrtf((float)rs1 + 2.0f);
        }
    }
    __syncthreads();

    // P6: preload wd0/wp1; xg = di1*vals0*x0[idx0]; xw; az -> x1
    Wl[(t >> 5) * 36 + (t & 31)] = wd[t];
    if (t < 32) gl[t] = wp[32 + t];
    {
        int r = t >> 3, cq = (t & 7) * 4;
        float s = di1[r] * vals0l[r];
        const float4 xv = *reinterpret_cast<const float4*>(
            &gx0[((size_t)b * NN + idx0l[r]) * HC + cq]);
        *reinterpret_cast<float4*>(&big1[r * 36 + cq]) =
            make_float4(s * xv.x, s * xv.y, s * xv.z, s * xv.w);
    }
    __syncthreads();
    xw_mm<128>(big1, Wl, nullptr, zbf, t);
    Wl[(t >> 5) * 36 + (t & 31)] = wd[1024 + t];
    az_u8(AgW, zbf, di1, bd, x1l, t);

    // P7: topk1 score + rank
    {
        float sn = 0.f;
        for (int i = 0; i < HC; ++i) { float v = gl[i]; sn += v * v; }
        sn = sqrtf(sn);
        if (t < 128) {
            float acc = 0.f;
#pragma unroll
            for (int i = 0; i < HC; ++i) {
                int c = (i + t) & 31;
                acc += x1l[t * 36 + c] * gl[c];
            }
            float s = ftanh(acc / sn);
            scl[t] = s;
            keys[t] = mkkey(s, t);
            inv1l[t] = -1;
        }
    }
    __syncthreads();
    rank_pass<128, 64>(scl, keys, idx1l, vals1l, inv1l, t);

    // P8: Ag1 via u8 dot4 + fused di2
    {
        u32* Gb = (u32*)zbf;
        for (int i = t; i < 2048; i += TPB) {
            int k = i >> 5, w = i & 31;
            int ir = idx1l[k];
            u32 word = AgW[ir * 32 + w];
            if (w == (ir >> 2)) word += (1u << (8 * (ir & 3)));
            Gb[k * 33 + w] = word;
        }
        __syncthreads();
        {
            int r = t >> 4, sq = t & 15;
            u32 racc[4] = {0, 0, 0, 0};
            for (int w = 0; w < 32; ++w) {
                u32 rv = Gb[r * 33 + w];
                racc[0] = dot4acc(rv, Gb[(sq * 4 + 0) * 33 + w], racc[0]);
                racc[1] = dot4acc(rv, Gb[(sq * 4 + 1) * 33 + w], racc[1]);
                racc[2] = dot4acc(rv, Gb[(sq * 4 + 2) * 33 + w], racc[2]);
                racc[3] = dot4acc(rv, Gb[(sq * 4 + 3) * 33 + w], racc[3]);
            }
            float4 o;
            o.x = (r == sq * 4 + 0) ? 0.f : (float)racc[0];
            o.y = (r == sq * 4 + 1) ? 0.f : (float)racc[1];
            o.z = (r == sq * 4 + 2) ? 0.f : (float)racc[2];
            o.w = (r == sq * 4 + 3) ? 0.f : (float)racc[3];
            *reinterpret_cast<float4*>(&big1[r * 64 + sq * 4]) = o;
            float ps = o.x + o.y + o.z + o.w;
            ps += __shfl_xor(ps, 1); ps += __shfl_xor(ps, 2);
            ps += __shfl_xor(ps, 4); ps += __shfl_xor(ps, 8);
            if (sq == 0) di2[r] = 1.0f / sqrtf(ps + 2.0f);
        }
        __syncthreads();
    }

    // P10: preload wp2; xg1; xw; preload wd2; az -> x2
    if (t < 32) gl[t] = wp[64 + t];
    if (t < 512) {
        float* xg1 = zbf + 2304;
        int r = t >> 3, cq = (t & 7) * 4;
        float s = di2[r] * vals1l[r];
        const float4 xv = *reinterpret_cast<const float4*>(&x1l[idx1l[r] * 36 + cq]);
        *reinterpret_cast<float4*>(&xg1[r * 36 + cq]) =
            make_float4(s * xv.x, s * xv.y, s * xv.z, s * xv.w);
    }
    __syncthreads();
    xw_mm<64>(zbf + 2304, Wl, nullptr, zbf, t);
    Wl[(t >> 5) * 36 + (t & 31)] = wd[2048 + t];
    az2_f32<64>(big1, zbf, di2, bd + 32, x2l, t);

    // P11: topk2 score + rank
    {
        float sn = 0.f;
        for (int i = 0; i < HC; ++i) { float v = gl[i]; sn += v * v; }
        sn = sqrtf(sn);
        if (t < 64) {
            float acc = 0.f;
#pragma unroll
            for (int i = 0; i < HC; ++i) {
                int c = (i + t) & 31;
                acc += x2l[t * 36 + c] * gl[c];
            }
            float s = ftanh(acc / sn);
            scl[t] = s;
            keys[t] = mkkey(s, t);
            inv2l[t] = -1;
        }
    }
    __syncthreads();
    rank_pass<64, 32>(scl, keys, idx2l, vals2l, inv2l, t);

    // P12: Ag2 + fused di3
    aug64_32(big1, idx2l, big2, di3, t);

    // P14: xg2; xw; preload wu0; az -> x3
    if (t < 256) {
        float* xg2 = zbf + 2304;
        int r = t >> 3, cq = (t & 7) * 4;
        float s = di3[r] * vals2l[r];
        const float4 xv = *reinterpret_cast<const float4*>(&x2l[idx2l[r] * 36 + cq]);
        *reinterpret_cast<float4*>(&xg2[r * 36 + cq]) =
            make_float4(s * xv.x, s * xv.y, s * xv.z, s * xv.w);
    }
    __syncthreads();
    xw_mm<32>(zbf + 2304, Wl, nullptr, zbf, t);
    Wl[(t >> 5) * 36 + (t & 31)] = wu[t];
    az_f32<32>(big2, zbf, di3, bd + 64, x3l, t);

    // P15: decode0 — fused merge+xw; az -> dec64
    xw_mrg<64>(x2l, x3l, inv2l, Wl, di2, zbf, t);
    Wl[(t >> 5) * 36 + (t & 31)] = wu[1024 + t];
    az2_f32<64>(big1, zbf, di2, bu, dec64, t);

    // P16: decode1 — fused merge+xw; az(Ag0u8) -> dec128
    xw_mrg<128>(x1l, dec64, inv1l, Wl, di1, zbf, t);
    az_u8(AgW, zbf, di1, bu + 32, dec128, t);

    // P17: prefetch merge into regs || sarr bit-walk; then pooled matvec
    {
        int c = t & 31, jg = t >> 5;
        float xv[8];
#pragma unroll
        for (int k = 0; k < 8; ++k) {
            int j = jg * 8 + k;
            float v = gx0[((size_t)b * NN + j) * HC + c];
            int ir = inv0l[j];
            if (ir >= 0) v += dec128[ir * 36 + c];
            xv[k] = v;
        }
        if (t < 256) {
            float acc = 0.f;
            u32 mw[8];
#pragma unroll
            for (int w = 0; w < 8; ++w) mw[w] = bitsl[t * 8 + w];
#pragma unroll
            for (int w = 0; w < 8; ++w) {
                u32 m = mw[w];
                int base = w * 32;
                while (m) {
                    int i = base + __ffs(m) - 1;
                    m &= m - 1;
                    acc += di0l[i];
                }
            }
            scl[t] = di0l[t] * (acc + 2.f * di0l[t]);
        }
        __syncthreads();
        float a2 = 0.f;
#pragma unroll
        for (int k = 0; k < 8; ++k) a2 += scl[jg * 8 + k] * xv[k];
        part[jg * 33 + c] = a2;
    }
    __syncthreads();
    if (t < 32) {
        float g = 0.f;
#pragma unroll
        for (int q = 0; q < 32; ++q) g += part[q * 33 + t];
        gl[t] = g;
    }
    __syncthreads();
    if (t < 256) {
        float a3 = 0.f;
        for (int cc = 0; cc < HC; ++cc) a3 += gl[cc] * wul[cc * EMBD + t];
        outp[b * EMBD + t] = a3 + 256.0f * bul[t];
    }
}

// ---------------------------------------------------------------------------
extern "C" void kernel_launch(void* const* d_in, const int* in_sizes, int n_in,
                              void* d_out, int out_size, void* d_ws, size_t ws_size,
                              hipStream_t stream) {
    const float* adj       = (const float*)d_in[0];
    const int*   xatom     = (const int*)d_in[1];
    const float* table     = (const float*)d_in[2];
    const float* w_down0   = (const float*)d_in[3];
    const float* b_down0   = (const float*)d_in[4];
    const float* w_down    = (const float*)d_in[5];
    const float* b_down    = (const float*)d_in[6];
    const float* w_pool    = (const float*)d_in[7];
    const float* w_up      = (const float*)d_in[8];
    const float* b_up      = (const float*)d_in[9];
    const float* w_up_last = (const float*)d_in[10];
    const float* b_up_last = (const float*)d_in[11];
    float* outp = (float*)d_out;

    float* ws = (float*)d_ws;
    float* TW  = ws;                       // 9*128*32 = 36864 f
    float* gx0 = ws + 36928;               // 256*256*32 f

    k_tw<<<(NF * NV * HC + 255) / 256, 256, 0, stream>>>(table, w_down0, TW);
    k_mega<<<NB, TPB, 0, stream>>>(adj, TW, xatom,
                                   b_down0, w_down, b_down, w_pool,
                                   w_up, b_up, w_up_last, b_up_last,
                                   gx0, outp);
}

// Round 14
// 87.649 us; speedup vs baseline: 1.2305x; 1.2305x over previous
//
#include <hip/hip_runtime.h>
#include <stdint.h>
#include <math.h>

#define NB 256      // graphs (B)
#define NN 256      // nodes at level 0
#define HC 32       // hidden channels
#define EMBD 256    // embedding dim
#define NF 9        // atom feat cols
#define NV 128      // padded vocab
#define TPB 1024    // 16 waves -> 4/SIMD (1 block/CU; grid == CU count)

typedef unsigned int u32;
typedef unsigned long long u64;

// ---------------------------------------------------------------------------
// TW[f,v,c] = sum_e table[f,v,e] * W0[e,c]
__global__ void k_tw(const float* __restrict__ table, const float* __restrict__ W0,
                     float* __restrict__ TW) {
    int gid = blockIdx.x * 256 + threadIdx.x;
    if (gid >= NF * NV * HC) return;
    int c = gid & 31;
    int v = (gid >> 5) & (NV - 1);
    int f = gid >> 12;
    const float* trow = table + (size_t)(f * NV + v) * EMBD;
    float acc = 0.f;
    for (int e = 0; e < EMBD; ++e) acc += trow[e] * W0[e * HC + c];
    TW[gid] = acc;
}

// ---------------------------------------------------------------------------
// LDS layout (byte offsets), total 136320 <= 160 KiB
#define SM_BITS   0        // u32[2048]
#define SM_DI0    8192     // f[256]
#define SM_BIG0   9216     // z0raw stride36 (36KB) -> Ag0 u8[128*128] (16KB)
#define SM_X1     46080    // f[128*36]
#define SM_BIG1   64512    // f[4608]: xg0 / Ag1 f32[64*64] / dec128[128*36]
#define SM_X2     82944    // f[64*36]
#define SM_BIG2   92160    // f[2304]: Ag2[1024] + x3@+1024; dec64[64*36]
#define SM_ZB     101376   // f[4608]: z stride36; xg@+2304; Gb u32[64*33]
#define SM_WG     119808   // Pg u32[128*9] / Wl f[32*36]  (4608B)
#define SM_SC     124416   // f[256]
#define SM_KEYS   125440   // u64[256]
#define SM_IDX0   127488
#define SM_VALS0  128000
#define SM_INV0   128512
#define SM_IDX1   129536
#define SM_VALS1  129792
#define SM_INV1   130048
#define SM_IDX2   130560
#define SM_VALS2  130688
#define SM_INV2   130816
#define SM_DI1    131072
#define SM_DI2    131584
#define SM_DI3    131840
#define SM_PART   131968   // f[1056] (32 groups x 33)
#define SM_GL     136192   // f[32]
#define SM_TOTAL  136320

__device__ __forceinline__ u32 dot4acc(u32 a, u32 b, u32 c) {
#if __has_builtin(__builtin_amdgcn_udot4)
    return __builtin_amdgcn_udot4(a, b, c, false);
#else
    return c + (a & 0xffu) * (b & 0xffu) + ((a >> 8) & 0xffu) * ((b >> 8) & 0xffu)
         + ((a >> 16) & 0xffu) * ((b >> 16) & 0xffu) + (a >> 24) * (b >> 24);
#endif
}

// fast tanh via hardware exp: rel err ~1e-6 (score gaps ~1e-3; safe for topk)
__device__ __forceinline__ float ftanh(float x) {
    float ax = fabsf(x);
    float e = __expf(-2.f * ax);
    float tv = (1.f - e) / (1.f + e);
    return copysignf(tv, x);
}

__device__ __forceinline__ u64 mkkey(float s, int r) {
    u32 bits = __float_as_uint(s);
    u32 m = ((int)bits < 0) ? 0xFFFFFFFFu : 0x80000000u;
    return ((u64)(~(bits ^ m)) << 32) | (u32)r;
}

template <int N, int K>
__device__ __forceinline__ void rank_pass(const float* sc, const u64* keys,
                                          int* idxo, float* valso, int* invo, int t) {
    if (t < N) {
        u64 mykey = keys[t];
        int rank = 0;
#pragma unroll 8
        for (int j = 0; j < N; ++j) rank += (keys[j] < mykey) ? 1 : 0;
        if (rank < K) {
            idxo[rank] = t;
            valso[rank] = sc[t];
            invo[t] = rank;
        }
    }
    __syncthreads();
}

template <int N>
__device__ __forceinline__ void az_f32(const float* A, const float* z,
                                       const float* di, const float* __restrict__ bias,
                                       float* xout, int t) {
    if (t < N * 8) {
        int r = t >> 3, cq = (t & 7) * 4;
        float a0 = 0.f, a1 = 0.f, a2 = 0.f, a3 = 0.f;
        for (int jj = 0; jj < N; ++jj) {
            const float4 zv = *reinterpret_cast<const float4*>(&z[jj * 36 + cq]);
            float a = A[jj * N + r];
            a0 += a * zv.x; a1 += a * zv.y; a2 += a * zv.z; a3 += a * zv.w;
        }
        float dr = di[r];
        float4 o;
        o.x = fmaxf(dr * (a0 + 2.f * z[r * 36 + cq + 0]) + bias[cq + 0], 0.f);
        o.y = fmaxf(dr * (a1 + 2.f * z[r * 36 + cq + 1]) + bias[cq + 1], 0.f);
        o.z = fmaxf(dr * (a2 + 2.f * z[r * 36 + cq + 2]) + bias[cq + 2], 0.f);
        o.w = fmaxf(dr * (a3 + 2.f * z[r * 36 + cq + 3]) + bias[cq + 3], 0.f);
        *reinterpret_cast<float4*>(&xout[r * 36 + cq]) = o;
    }
    __syncthreads();
}

template <int N>
__device__ __forceinline__ void az2_f32(const float* A, const float* z,
                                        const float* di, const float* __restrict__ bias,
                                        float* xout, int t) {
    if (t < N * 4) {
        int g = t >> 3, cq = (t & 7) * 4;
        float a0[4] = {0.f, 0.f, 0.f, 0.f};
        float a1[4] = {0.f, 0.f, 0.f, 0.f};
        for (int jj = 0; jj < N; ++jj) {
            const float4 zv = *reinterpret_cast<const float4*>(&z[jj * 36 + cq]);
            const float2 av = *reinterpret_cast<const float2*>(&A[jj * N + 2 * g]);
            a0[0] += av.x * zv.x; a0[1] += av.x * zv.y;
            a0[2] += av.x * zv.z; a0[3] += av.x * zv.w;
            a1[0] += av.y * zv.x; a1[1] += av.y * zv.y;
            a1[2] += av.y * zv.z; a1[3] += av.y * zv.w;
        }
#pragma unroll
        for (int i = 0; i < 2; ++i) {
            int r = 2 * g + i;
            const float* ai = i ? a1 : a0;
            float dr = di[r];
            float4 o;
            o.x = fmaxf(dr * (ai[0] + 2.f * z[r * 36 + cq + 0]) + bias[cq + 0], 0.f);
            o.y = fmaxf(dr * (ai[1] + 2.f * z[r * 36 + cq + 1]) + bias[cq + 1], 0.f);
            o.z = fmaxf(dr * (ai[2] + 2.f * z[r * 36 + cq + 2]) + bias[cq + 2], 0.f);
            o.w = fmaxf(dr * (ai[3] + 2.f * z[r * 36 + cq + 3]) + bias[cq + 3], 0.f);
            *reinterpret_cast<float4*>(&xout[r * 36 + cq]) = o;
        }
    }
    __syncthreads();
}

__device__ __forceinline__ void az_u8(const u32* AgW, const float* z,
                                      const float* di, const float* __restrict__ bias,
                                      float* xout, int t) {
    if (t < 256) {
        int g = t >> 3, cq = (t & 7) * 4;
        float ax[4][4];
#pragma unroll
        for (int i = 0; i < 4; ++i) { ax[i][0] = ax[i][1] = ax[i][2] = ax[i][3] = 0.f; }
        for (int jj = 0; jj < 128; ++jj) {
            const float4 zv = *reinterpret_cast<const float4*>(&z[jj * 36 + cq]);
            u32 w = AgW[jj * 32 + g];
            float f0 = (float)(w & 255u), f1 = (float)((w >> 8) & 255u);
            float f2 = (float)((w >> 16) & 255u), f3 = (float)(w >> 24);
            ax[0][0] += f0 * zv.x; ax[0][1] += f0 * zv.y; ax[0][2] += f0 * zv.z; ax[0][3] += f0 * zv.w;
            ax[1][0] += f1 * zv.x; ax[1][1] += f1 * zv.y; ax[1][2] += f1 * zv.z; ax[1][3] += f1 * zv.w;
            ax[2][0] += f2 * zv.x; ax[2][1] += f2 * zv.y; ax[2][2] += f2 * zv.z; ax[2][3] += f2 * zv.w;
            ax[3][0] += f3 * zv.x; ax[3][1] += f3 * zv.y; ax[3][2] += f3 * zv.z; ax[3][3] += f3 * zv.w;
        }
#pragma unroll
        for (int i = 0; i < 4; ++i) {
            int r = 4 * g + i;
            float dr = di[r];
            float4 o;
            o.x = fmaxf(dr * (ax[i][0] + 2.f * z[r * 36 + cq + 0]) + bias[cq + 0], 0.f);
            o.y = fmaxf(dr * (ax[i][1] + 2.f * z[r * 36 + cq + 1]) + bias[cq + 1], 0.f);
            o.z = fmaxf(dr * (ax[i][2] + 2.f * z[r * 36 + cq + 2]) + bias[cq + 2], 0.f);
            o.w = fmaxf(dr * (ax[i][3] + 2.f * z[r * 36 + cq + 3]) + bias[cq + 3], 0.f);
            *reinterpret_cast<float4*>(&xout[r * 36 + cq]) = o;
        }
    }
    __syncthreads();
}

template <int N>
__device__ __forceinline__ void xw_mm(const float* xin, const float* Wl,
                                      const float* pre, float* zout, int t) {
    for (int i = t; i < N * 8; i += TPB) {
        int r = i >> 3, cq = (i & 7) * 4;
        float a0 = 0.f, a1 = 0.f, a2 = 0.f, a3 = 0.f;
#pragma unroll 8
        for (int e = 0; e < 32; ++e) {
            float xv = xin[r * 36 + e];
            const float4 wv = *reinterpret_cast<const float4*>(&Wl[e * 36 + cq]);
            a0 += xv * wv.x; a1 += xv * wv.y; a2 += xv * wv.z; a3 += xv * wv.w;
        }
        float p = pre ? pre[r] : 1.f;
        *reinterpret_cast<float4*>(&zout[r * 36 + cq]) =
            make_float4(a0 * p, a1 * p, a2 * p, a3 * p);
    }
    __syncthreads();
}

template <int N>
__device__ __forceinline__ void xw_mrg(const float* xin, const float* xup,
                                       const int* invl, const float* Wl,
                                       const float* pre, float* zout, int t) {
    for (int i = t; i < N * 8; i += TPB) {
        int r = i >> 3, cq = (i & 7) * 4;
        int ir = invl[r];
        const float* ux = (ir >= 0) ? &xup[ir * 36] : nullptr;
        float a0 = 0.f, a1 = 0.f, a2 = 0.f, a3 = 0.f;
#pragma unroll 8
        for (int e = 0; e < 32; ++e) {
            float xv = xin[r * 36 + e];
            if (ux) xv += ux[e];
            const float4 wv = *reinterpret_cast<const float4*>(&Wl[e * 36 + cq]);
            a0 += xv * wv.x; a1 += xv * wv.y; a2 += xv * wv.z; a3 += xv * wv.w;
        }
        float p = pre[r];
        *reinterpret_cast<float4*>(&zout[r * 36 + cq]) =
            make_float4(a0 * p, a1 * p, a2 * p, a3 * p);
    }
    __syncthreads();
}

__device__ __forceinline__ void aug64_32(const float* A, const int* idxl,
                                         float* out, float* di3, int t) {
    if (t < 256) {
        int rr0 = t >> 3, sb = (t & 7) * 4;
        int ir = idxl[rr0];
        int is0 = idxl[sb], is1 = idxl[sb + 1], is2 = idxl[sb + 2], is3 = idxl[sb + 3];
        float c0 = 0.f, c1 = 0.f, c2 = 0.f, c3 = 0.f;
        for (int jj = 0; jj < 16; ++jj) {
            int jq = ((jj + rr0) & 15) * 4;
            const float4 ar = *reinterpret_cast<const float4*>(&A[ir * 64 + jq]);
            const float4 v0 = *reinterpret_cast<const float4*>(&A[is0 * 64 + jq]);
            const float4 v1 = *reinterpret_cast<const float4*>(&A[is1 * 64 + jq]);
            const float4 v2 = *reinterpret_cast<const float4*>(&A[is2 * 64 + jq]);
            const float4 v3 = *reinterpret_cast<const float4*>(&A[is3 * 64 + jq]);
            c0 += ar.x * v0.x + ar.y * v0.y + ar.z * v0.z + ar.w * v0.w;
            c1 += ar.x * v1.x + ar.y * v1.y + ar.z * v1.z + ar.w * v1.w;
            c2 += ar.x * v2.x + ar.y * v2.y + ar.z * v2.z + ar.w * v2.w;
            c3 += ar.x * v3.x + ar.y * v3.y + ar.z * v3.z + ar.w * v3.w;
        }
        float o0 = c0 + 2.f * A[ir * 64 + is0] + (ir == is0 ? 1.f : 0.f);
        float o1 = c1 + 2.f * A[ir * 64 + is1] + (ir == is1 ? 1.f : 0.f);
        float o2 = c2 + 2.f * A[ir * 64 + is2] + (ir == is2 ? 1.f : 0.f);
        float o3 = c3 + 2.f * A[ir * 64 + is3] + (ir == is3 ? 1.f : 0.f);
        if (rr0 == sb + 0) o0 = 0.f;
        if (rr0 == sb + 1) o1 = 0.f;
        if (rr0 == sb + 2) o2 = 0.f;
        if (rr0 == sb + 3) o3 = 0.f;
        *reinterpret_cast<float4*>(&out[rr0 * 32 + sb]) = make_float4(o0, o1, o2, o3);
        float ps = o0 + o1 + o2 + o3;
        ps += __shfl_xor(ps, 1);
        ps += __shfl_xor(ps, 2);
        ps += __shfl_xor(ps, 4);
        if ((t & 7) == 0) di3[rr0] = 1.0f / sqrtf(ps + 2.0f);
    }
    __syncthreads();
}

// ---------------------------------------------------------------------------
__global__ void __launch_bounds__(TPB, 1) k_mega(
    const float* __restrict__ adj, const float* __restrict__ TW,
    const int* __restrict__ xa,
    const float* __restrict__ bd0, const float* __restrict__ wd,
    const float* __restrict__ bd, const float* __restrict__ wp,
    const float* __restrict__ wu, const float* __restrict__ bu,
    const float* __restrict__ wul, const float* __restrict__ bul,
    float* __restrict__ gx0, float* __restrict__ outp) {
    __shared__ __align__(16) char SM[SM_TOTAL];
    u32*   bitsl = (u32*)(SM + SM_BITS);
    float* di0l  = (float*)(SM + SM_DI0);
    float* z0    = (float*)(SM + SM_BIG0);
    u32*   AgW   = (u32*)(SM + SM_BIG0);
    float* x1l   = (float*)(SM + SM_X1);
    float* big1  = (float*)(SM + SM_BIG1);
    float* x2l   = (float*)(SM + SM_X2);
    float* big2  = (float*)(SM + SM_BIG2);
    float* zbf   = (float*)(SM + SM_ZB);
    u32*   Pg    = (u32*)(SM + SM_WG);
    float* Wl    = (float*)(SM + SM_WG);
    float* scl   = (float*)(SM + SM_SC);
    u64*   keys  = (u64*)(SM + SM_KEYS);
    int*   idx0l = (int*)(SM + SM_IDX0);
    float* vals0l= (float*)(SM + SM_VALS0);
    int*   inv0l = (int*)(SM + SM_INV0);
    int*   idx1l = (int*)(SM + SM_IDX1);
    float* vals1l= (float*)(SM + SM_VALS1);
    int*   inv1l = (int*)(SM + SM_INV1);
    int*   idx2l = (int*)(SM + SM_IDX2);
    float* vals2l= (float*)(SM + SM_VALS2);
    int*   inv2l = (int*)(SM + SM_INV2);
    float* di1   = (float*)(SM + SM_DI1);
    float* di2   = (float*)(SM + SM_DI2);
    float* di3   = (float*)(SM + SM_DI3);
    float* part  = (float*)(SM + SM_PART);
    float* gl    = (float*)(SM + SM_GL);
    float* x3l   = big2 + 1024;
    float* dec64 = big2;
    float* dec128= big1;

    int b = blockIdx.x, t = threadIdx.x;

    // P1: z0raw = h @ W0 via TW gather
    for (int i = t; i < 2048; i += TPB) {
        int node = i >> 3, cq = (i & 7) * 4;
        const int* xr = xa + (b * NN + node) * NF;
        float ax = 0.f, ay = 0.f, azz = 0.f, aw = 0.f;
#pragma unroll
        for (int f = 0; f < NF; ++f) {
            int v = xr[f];
            const float4 tw = *reinterpret_cast<const float4*>(&TW[((f << 7) + v) * HC + cq]);
            ax += tw.x; ay += tw.y; azz += tw.z; aw += tw.w;
        }
        *reinterpret_cast<float4*>(&z0[node * 36 + cq]) = make_float4(ax, ay, azz, aw);
    }

    // P0: pack adjacency + di0 — float4 row loads + shuffle nibble pack
    {
        int lane = t & 63, wv = t >> 6;
        for (int row = wv; row < NN; row += 16) {
            const float4 av = *reinterpret_cast<const float4*>(
                &adj[((size_t)b * NN + row) * NN + lane * 4]);
            u32 nib = (av.x != 0.f ? 1u : 0u) | (av.y != 0.f ? 2u : 0u)
                    | (av.z != 0.f ? 4u : 0u) | (av.w != 0.f ? 8u : 0u);
            int pc = __popc(nib);
            u32 w2 = nib | (__shfl_xor(nib, 1) << 4);
            u32 w4 = w2 | (__shfl_xor(w2, 2) << 8);
            u32 w8 = w4 | (__shfl_xor(w4, 4) << 16);
            if ((lane & 7) == 0) bitsl[row * 8 + (lane >> 3)] = w8;
            pc += __shfl_xor(pc, 1);  pc += __shfl_xor(pc, 2);
            pc += __shfl_xor(pc, 4);  pc += __shfl_xor(pc, 8);
            pc += __shfl_xor(pc, 16); pc += __shfl_xor(pc, 32);
            if (lane == 0) di0l[row] = 1.0f / sqrtf((float)pc + 2.0f);
        }
    }
    if (t < 32) gl[t] = wp[t];
    __syncthreads();

    // P2: GCN0 sparse + topk0 scores/keys; x0 -> global
    {
        float sn0 = 0.f;
        for (int i = 0; i < HC; ++i) { float v = gl[i]; sn0 += v * v; }
        sn0 = sqrtf(sn0);
        int r0 = t >> 3, cq = (t & 7) * 4;
        for (int tile = 0; tile < 2; ++tile) {
            int r = tile * 128 + r0;
            u32 mw[8];
#pragma unroll
            for (int w = 0; w < 8; ++w) mw[w] = bitsl[r * 8 + w];
            float a0 = 0.f, a1 = 0.f, a2 = 0.f, a3 = 0.f;
#pragma unroll
            for (int w = 0; w < 8; ++w) {
                u32 m = mw[w];
                int base = w * 32;
                while (m) {
                    int j = base + __ffs(m) - 1;
                    m &= m - 1;
                    float dj = di0l[j];
                    const float4 zv = *reinterpret_cast<const float4*>(&z0[j * 36 + cq]);
                    a0 += dj * zv.x; a1 += dj * zv.y; a2 += dj * zv.z; a3 += dj * zv.w;
                }
            }
            float dr = di0l[r];
            float o0 = fmaxf(dr * (a0 + 2.f * dr * z0[r * 36 + cq + 0]) + bd0[cq + 0], 0.f);
            float o1 = fmaxf(dr * (a1 + 2.f * dr * z0[r * 36 + cq + 1]) + bd0[cq + 1], 0.f);
            float o2 = fmaxf(dr * (a2 + 2.f * dr * z0[r * 36 + cq + 2]) + bd0[cq + 2], 0.f);
            float o3 = fmaxf(dr * (a3 + 2.f * dr * z0[r * 36 + cq + 3]) + bd0[cq + 3], 0.f);
            *reinterpret_cast<float4*>(&gx0[((size_t)b * NN + r) * HC + cq]) =
                make_float4(o0, o1, o2, o3);
            float pd = o0 * gl[cq] + o1 * gl[cq + 1] + o2 * gl[cq + 2] + o3 * gl[cq + 3];
            pd += __shfl_xor(pd, 1);
            pd += __shfl_xor(pd, 2);
            pd += __shfl_xor(pd, 4);
            if ((t & 7) == 0) {
                float s = ftanh(pd / sn0);
                scl[r] = s;
                keys[r] = mkkey(s, r);
                inv0l[r] = -1;
            }
        }
    }
    __syncthreads();

    // P3: topk0 rank
    rank_pass<256, 128>(scl, keys, idx0l, vals0l, inv0l, t);

    // P4: gathered bits -> popcount augment -> Ag0 u8, fused di1
    {
        int r = t >> 3, w = t & 7;
        int row = idx0l[r];
        u32 word = bitsl[row * 8 + w];
        if (w == (row >> 5)) word |= (1u << (row & 31));
        Pg[r * 9 + w] = word;
    }
    __syncthreads();
    {
        int rr0 = t >> 4, sb = (t & 15) * 4;
        u32 rw[2][8];
#pragma unroll
        for (int rt = 0; rt < 2; ++rt)
#pragma unroll
            for (int w = 0; w < 8; ++w) rw[rt][w] = Pg[(rt * 64 + rr0) * 9 + w];
        int rs0 = 0, rs1 = 0;
#pragma unroll
        for (int k4 = 0; k4 < 2; ++k4) {
            int s0 = sb + 64 * k4;
            u32 cnt[2][4];
#pragma unroll
            for (int a = 0; a < 2; ++a) { cnt[a][0] = cnt[a][1] = cnt[a][2] = cnt[a][3] = 0; }
#pragma unroll
            for (int u = 0; u < 4; ++u) {
                int s = s0 + u;
#pragma unroll
                for (int w = 0; w < 8; ++w) {
                    u32 sw = Pg[s * 9 + w];
                    cnt[0][u] += __popc(rw[0][w] & sw);
                    cnt[1][u] += __popc(rw[1][w] & sw);
                }
            }
#pragma unroll
            for (int rt = 0; rt < 2; ++rt) {
                int r = rt * 64 + rr0;
                if (r >= s0 && r < s0 + 4) cnt[rt][r - s0] = 0;
                AgW[r * 32 + (s0 >> 2)] =
                    cnt[rt][0] | (cnt[rt][1] << 8) | (cnt[rt][2] << 16) | (cnt[rt][3] << 24);
                int sum4 = (int)(cnt[rt][0] + cnt[rt][1] + cnt[rt][2] + cnt[rt][3]);
                if (rt == 0) rs0 += sum4; else rs1 += sum4;
            }
        }
        rs0 += __shfl_xor(rs0, 1); rs0 += __shfl_xor(rs0, 2);
        rs0 += __shfl_xor(rs0, 4); rs0 += __shfl_xor(rs0, 8);
        rs1 += __shfl_xor(rs1, 1); rs1 += __shfl_xor(rs1, 2);
        rs1 += __shfl_xor(rs1, 4); rs1 += __shfl_xor(rs1, 8);
        if ((t & 15) == 0) {
            di1[rr0]      = 1.0f / sqrtf((float)rs0 + 2.0f);
            di1[rr0 + 64] = 1.0f / sqrtf((float)rs1 + 2.0f);
        }
    }
    __syncthreads();

    // P6: preload wd0/wp1; xg = di1*vals0*x0[idx0]; xw; az -> x1
    Wl[(t >> 5) * 36 + (t & 31)] = wd[t];
    if (t < 32) gl[t] = wp[32 + t];
    {
        int r = t >> 3, cq = (t & 7) * 4;
        float s = di1[r] * vals0l[r];
        const float4 xv = *reinterpret_cast<const float4*>(
            &gx0[((size_t)b * NN + idx0l[r]) * HC + cq]);
        *reinterpret_cast<float4*>(&big1[r * 36 + cq]) =
            make_float4(s * xv.x, s * xv.y, s * xv.z, s * xv.w);
    }
    __syncthreads();
    xw_mm<128>(big1, Wl, nullptr, zbf, t);
    Wl[(t >> 5) * 36 + (t & 31)] = wd[1024 + t];
    az_u8(AgW, zbf, di1, bd, x1l, t);

    // P7: topk1 score + rank
    {
        float sn = 0.f;
        for (int i = 0; i < HC; ++i) { float v = gl[i]; sn += v * v; }
        sn = sqrtf(sn);
        if (t < 128) {
            float acc = 0.f;
#pragma unroll
            for (int i = 0; i < HC; ++i) {
                int c = (i + t) & 31;
                acc += x1l[t * 36 + c] * gl[c];
            }
            float s = ftanh(acc / sn);
            scl[t] = s;
            keys[t] = mkkey(s, t);
            inv1l[t] = -1;
        }
    }
    __syncthreads();
    rank_pass<128, 64>(scl, keys, idx1l, vals1l, inv1l, t);

    // P8: Ag1 via u8 dot4 + fused di2
    {
        u32* Gb = (u32*)zbf;
        for (int i = t; i < 2048; i += TPB) {
            int k = i >> 5, w = i & 31;
            int ir = idx1l[k];
            u32 word = AgW[ir * 32 + w];
            if (w == (ir >> 2)) word += (1u << (8 * (ir & 3)));
            Gb[k * 33 + w] = word;
        }
        __syncthreads();
        {
            int r = t >> 4, sq = t & 15;
            u32 racc[4] = {0, 0, 0, 0};
            for (int w = 0; w < 32; ++w) {
                u32 rv = Gb[r * 33 + w];
                racc[0] = dot4acc(rv, Gb[(sq * 4 + 0) * 33 + w], racc[0]);
                racc[1] = dot4acc(rv, Gb[(sq * 4 + 1) * 33 + w], racc[1]);
                racc[2] = dot4acc(rv, Gb[(sq * 4 + 2) * 33 + w], racc[2]);
                racc[3] = dot4acc(rv, Gb[(sq * 4 + 3) * 33 + w], racc[3]);
            }
            float4 o;
            o.x = (r == sq * 4 + 0) ? 0.f : (float)racc[0];
            o.y = (r == sq * 4 + 1) ? 0.f : (float)racc[1];
            o.z = (r == sq * 4 + 2) ? 0.f : (float)racc[2];
            o.w = (r == sq * 4 + 3) ? 0.f : (float)racc[3];
            *reinterpret_cast<float4*>(&big1[r * 64 + sq * 4]) = o;
            float ps = o.x + o.y + o.z + o.w;
            ps += __shfl_xor(ps, 1); ps += __shfl_xor(ps, 2);
            ps += __shfl_xor(ps, 4); ps += __shfl_xor(ps, 8);
            if (sq == 0) di2[r] = 1.0f / sqrtf(ps + 2.0f);
        }
        __syncthreads();
    }

    // P10: preload wp2; xg1; xw; preload wd2; az -> x2
    if (t < 32) gl[t] = wp[64 + t];
    if (t < 512) {
        float* xg1 = zbf + 2304;
        int r = t >> 3, cq = (t & 7) * 4;
        float s = di2[r] * vals1l[r];
        const float4 xv = *reinterpret_cast<const float4*>(&x1l[idx1l[r] * 36 + cq]);
        *reinterpret_cast<float4*>(&xg1[r * 36 + cq]) =
            make_float4(s * xv.x, s * xv.y, s * xv.z, s * xv.w);
    }
    __syncthreads();
    xw_mm<64>(zbf + 2304, Wl, nullptr, zbf, t);
    Wl[(t >> 5) * 36 + (t & 31)] = wd[2048 + t];
    az2_f32<64>(big1, zbf, di2, bd + 32, x2l, t);

    // P11: topk2 score + rank
    {
        float sn = 0.f;
        for (int i = 0; i < HC; ++i) { float v = gl[i]; sn += v * v; }
        sn = sqrtf(sn);
        if (t < 64) {
            float acc = 0.f;
#pragma unroll
            for (int i = 0; i < HC; ++i) {
                int c = (i + t) & 31;
                acc += x2l[t * 36 + c] * gl[c];
            }
            float s = ftanh(acc / sn);
            scl[t] = s;
            keys[t] = mkkey(s, t);
            inv2l[t] = -1;
        }
    }
    __syncthreads();
    rank_pass<64, 32>(scl, keys, idx2l, vals2l, inv2l, t);

    // P12: Ag2 + fused di3
    aug64_32(big1, idx2l, big2, di3, t);

    // P14: xg2; xw; preload wu0; az -> x3
    if (t < 256) {
        float* xg2 = zbf + 2304;
        int r = t >> 3, cq = (t & 7) * 4;
        float s = di3[r] * vals2l[r];
        const float4 xv = *reinterpret_cast<const float4*>(&x2l[idx2l[r] * 36 + cq]);
        *reinterpret_cast<float4*>(&xg2[r * 36 + cq]) =
            make_float4(s * xv.x, s * xv.y, s * xv.z, s * xv.w);
    }
    __syncthreads();
    xw_mm<32>(zbf + 2304, Wl, nullptr, zbf, t);
    Wl[(t >> 5) * 36 + (t & 31)] = wu[t];
    az_f32<32>(big2, zbf, di3, bd + 64, x3l, t);

    // P15: decode0 — fused merge+xw; az -> dec64
    xw_mrg<64>(x2l, x3l, inv2l, Wl, di2, zbf, t);
    Wl[(t >> 5) * 36 + (t & 31)] = wu[1024 + t];
    az2_f32<64>(big1, zbf, di2, bu, dec64, t);

    // P16: decode1 — fused merge+xw; az(Ag0u8) -> dec128
    xw_mrg<128>(x1l, dec64, inv1l, Wl, di1, zbf, t);
    az_u8(AgW, zbf, di1, bu + 32, dec128, t);

    // P17: prefetch merge into regs || sarr bit-walk; then pooled matvec
    {
        int c = t & 31, jg = t >> 5;
        float xv[8];
#pragma unroll
        for (int k = 0; k < 8; ++k) {
            int j = jg * 8 + k;
            float v = gx0[((size_t)b * NN + j) * HC + c];
            int ir = inv0l[j];
            if (ir >= 0) v += dec128[ir * 36 + c];
            xv[k] = v;
        }
        if (t < 256) {
            float acc = 0.f;
            u32 mw[8];
#pragma unroll
            for (int w = 0; w < 8; ++w) mw[w] = bitsl[t * 8 + w];
#pragma unroll
            for (int w = 0; w < 8; ++w) {
                u32 m = mw[w];
                int base = w * 32;
                while (m) {
                    int i = base + __ffs(m) - 1;
                    m &= m - 1;
                    acc += di0l[i];
                }
            }
            scl[t] = di0l[t] * (acc + 2.f * di0l[t]);
        }
        __syncthreads();
        float a2 = 0.f;
#pragma unroll
        for (int k = 0; k < 8; ++k) a2 += scl[jg * 8 + k] * xv[k];
        part[jg * 33 + c] = a2;
    }
    __syncthreads();
    if (t < 32) {
        float g = 0.f;
#pragma unroll
        for (int q = 0; q < 32; ++q) g += part[q * 33 + t];
        gl[t] = g;
    }
    __syncthreads();
    if (t < 256) {
        float a3 = 0.f;
        for (int cc = 0; cc < HC; ++cc) a3 += gl[cc] * wul[cc * EMBD + t];
        outp[b * EMBD + t] = a3 + 256.0f * bul[t];
    }
}

// ---------------------------------------------------------------------------
extern "C" void kernel_launch(void* const* d_in, const int* in_sizes, int n_in,
                              void* d_out, int out_size, void* d_ws, size_t ws_size,
                              hipStream_t stream) {
    const float* adj       = (const float*)d_in[0];
    const int*   xatom     = (const int*)d_in[1];
    const float* table     = (const float*)d_in[2];
    const float* w_down0   = (const float*)d_in[3];
    const float* b_down0   = (const float*)d_in[4];
    const float* w_down    = (const float*)d_in[5];
    const float* b_down    = (const float*)d_in[6];
    const float* w_pool    = (const float*)d_in[7];
    const float* w_up      = (const float*)d_in[8];
    const float* b_up      = (const float*)d_in[9];
    const float* w_up_last = (const float*)d_in[10];
    const float* b_up_last = (const float*)d_in[11];
    float* outp = (float*)d_out;

    float* ws = (float*)d_ws;
    float* TW  = ws;                       // 9*128*32 = 36864 f
    float* gx0 = ws + 36928;               // 256*256*32 f

    k_tw<<<(NF * NV * HC + 255) / 256, 256, 0, stream>>>(table, w_down0, TW);
    k_mega<<<NB, TPB, 0, stream>>>(adj, TW, xatom,
                                   b_down0, w_down, b_down, w_pool,
                                   w_up, b_up, w_up_last, b_up_last,
                                   gx0, outp);
}